// Round 1
// baseline (225.304 us; speedup 1.0000x reference)
//
#include <hip/hip_runtime.h>

#define NUM_ACT 64
#define SPLINE_SIZE 51
// x is [32, 64, 128, 128]: one (n,c) plane = 128*128 = 16384 elems = 4096 float4.
// Plane-per-block: grid = 32*64 = 2048 blocks (8/CU, all co-resident, uniform work).
//   - channel index is block-uniform: c = blockIdx.x & 63
//   - coef table + scale loaded ONCE per plane (vs 8x in the 16384-block version)
// Each of 256 threads handles 16 float4 in a 2-stage register pipeline:
// prefetch the next group of 4 float4 while computing/storing the current 4,
// so vmcnt never drains to 0 inside the main loop.

typedef float f32x4 __attribute__((ext_vector_type(4)));

__global__ __launch_bounds__(256) void linear_spline_kernel(
    const f32x4* __restrict__ x4,
    const float* __restrict__ coef,
    const float* __restrict__ scale,
    f32x4* __restrict__ out4)
{
    __shared__ float lcoef[SPLINE_SIZE];

    const int plane = blockIdx.x;              // 0..2047  == n*64 + c
    const int c = plane & (NUM_ACT - 1);       // block-uniform channel

    const float s  = scale[c];                 // scalar load (c is SGPR-uniform)
    const float rs = 1.0f / s;

    // Fold the final /s into the coefficient table: (c1*fr + c0*(1-fr))*rs
    // == (c1*rs)*fr + (c0*rs)*(1-fr). Exact for s==1 (test input).
    if (threadIdx.x < SPLINE_SIZE)
        lcoef[threadIdx.x] = coef[c * SPLINE_SIZE + threadIdx.x] * rs;

    // Fold *s and *(1/grid) into one multiply: t = x*(s*6.25f).
    // 6.25f == fl(1/0.16f) exactly; for s==1, sg==6.25f and t is bit-identical
    // to the previous kernel's (x*s)*6.25f.
    const float sg = s * 6.25f;

    __syncthreads();

    const int base = plane * 4096 + threadIdx.x;   // float4 index

    f32x4 cur[4], nxt[4];
#pragma unroll
    for (int k = 0; k < 4; ++k)
        cur[k] = __builtin_nontemporal_load(&x4[base + k * 256]);

#pragma unroll
    for (int g = 0; g < 4; ++g) {
        // Prefetch next group before touching cur -> compiler keeps these
        // 4 loads in flight (s_waitcnt vmcnt(4)) across the compute+store.
        if (g < 3) {
#pragma unroll
            for (int k = 0; k < 4; ++k)
                nxt[k] = __builtin_nontemporal_load(&x4[base + (g + 1) * 1024 + k * 256]);
        }
#pragma unroll
        for (int k = 0; k < 4; ++k) {
            f32x4 xv = cur[k];
            f32x4 ov;
#pragma unroll
            for (int e = 0; e < 4; ++e) {
                float t = xv[e] * sg;
                // floor-then-int-clamp == reference's clamp-then-floor at the
                // boundaries (xs>3.84 -> t>=24.000001 -> fl=24; xs<-4 ->
                // -4.0f/0.16f == -25.0f exactly -> floor -25 == clamp -25);
                // interior 1-ulp floor flips are continuous -> harmless.
                int fl = (int)floorf(t);
                fl = min(max(fl, -(SPLINE_SIZE / 2)), SPLINE_SIZE / 2 - 1); // [-25,24]
                float fr = t - (float)fl;          // fracs from UNclamped t
                int li = fl + SPLINE_SIZE / 2;     // [0, 49]
                float c0 = lcoef[li];
                float c1 = lcoef[li + 1];
                ov[e] = c0 + (c1 - c0) * fr;       // sub+fma form, <=1 ulp vs lerp
            }
            __builtin_nontemporal_store(ov, &out4[base + g * 1024 + k * 256]);
        }
        if (g < 3) {
#pragma unroll
            for (int k = 0; k < 4; ++k) cur[k] = nxt[k];
        }
    }
}

extern "C" void kernel_launch(void* const* d_in, const int* in_sizes, int n_in,
                              void* d_out, int out_size, void* d_ws, size_t ws_size,
                              hipStream_t stream) {
    const float* x     = (const float*)d_in[0];
    const float* coef  = (const float*)d_in[1];
    const float* scale = (const float*)d_in[2];
    float* out = (float*)d_out;

    int n      = in_sizes[0];      // 33,554,432 elems
    int n4     = n >> 2;           // 8,388,608 float4
    int planes = n4 / 4096;        // 2048 blocks == 32*64 (n,c) planes, exact

    linear_spline_kernel<<<planes, 256, 0, stream>>>(
        (const f32x4*)x, coef, scale, (f32x4*)out);
}